// Round 9
// baseline (171.854 us; speedup 1.0000x reference)
//
#include <hip/hip_runtime.h>
#include <hip/hip_bf16.h>
#include <stdint.h>

#define T_TOKENS 8192
#define F_DIM    2048
#define E_EXP    16
#define R_RANK   16
#define O_DIM    2048
#define KDIM     (E_EXP * R_RANK)   // 256

typedef short v8s __attribute__((ext_vector_type(8)));
typedef float v4f __attribute__((ext_vector_type(4)));

#define AS1 __attribute__((address_space(1)))
#define AS3 __attribute__((address_space(3)))

__device__ __forceinline__ uint16_t f2bf(float f) {
  uint32_t u = __builtin_bit_cast(uint32_t, f);
  u += 0x7fffu + ((u >> 16) & 1u);   // round-to-nearest-even
  return (uint16_t)(u >> 16);
}

// async global->LDS, 16B per lane; LDS dest = wave-uniform base + lane*16
__device__ __forceinline__ void g2lds16(const void* g, void* l) {
  __builtin_amdgcn_global_load_lds((const AS1 void*)g, (AS3 void*)l, 16, 0, 0);
}

// ---------------------------------------------------------------------------
// K1: route_stream (R8-exact: best per-dispatch profile, 41.0 us, VGPR 44).
// 2-token reuse + depth-1 k-pipeline. Grid 9 x 128: c 0..7 route chunks,
// c == 8: weight prep (x-interleaved). Partials: [(c*4+e4)*8192 + t].
// ---------------------------------------------------------------------------
__global__ __launch_bounds__(256) void route_stream(
    const float* __restrict__ x, const float* __restrict__ P,
    const float* __restrict__ A, const float* __restrict__ Bst,
    uint16_t* __restrict__ xb, float4* __restrict__ partials4,
    uint16_t* __restrict__ Ab, uint16_t* __restrict__ Bb) {
  __shared__ float ps[16 * 256];   // 16 KB, linear (g2lds dest)
  const int tid = threadIdx.x;
  const int c   = blockIdx.x;      // 0..7 route chunk; 8 = weight prep
  const int by  = blockIdx.y;      // 0..127

  if (c == 8) {
    const int base = by * 4096;
    #pragma unroll
    for (int p = 0; p < 16; ++p) {
      const int i = base + p * 256 + tid;
      Ab[i] = f2bf(A[i]);
      const int k = i & (KDIM - 1);
      const int o = i >> 8;
      Bb[i] = f2bf(Bst[((size_t)(k >> 4) * O_DIM + o) * R_RANK + (k & 15)]);
    }
    return;
  }

  const int f0 = c * 256;
  #pragma unroll
  for (int p = 0; p < 4; ++p) {
    const int G = p * 256 + tid;                  // 0..1023
    g2lds16(&P[(size_t)(G >> 6) * F_DIM + f0 + (G & 63) * 4],
            (char*)ps + (p * 256 + (tid >> 6) * 64) * 16);
  }
  __syncthreads();

  const int sub = tid & 7;         // 32-col slice: cols {sub*4 + k*32}
  const int tg  = tid >> 3;        // 0..31
  const int r0  = by * 64 + tg;    // token A
  const int r1  = r0 + 32;         // token B
  const float* xr0 = x  + (size_t)r0 * F_DIM + f0 + sub * 4;
  const float* xr1 = x  + (size_t)r1 * F_DIM + f0 + sub * 4;
  uint16_t*    xw0 = xb + (size_t)r0 * F_DIM + f0 + sub * 4;
  uint16_t*    xw1 = xb + (size_t)r1 * F_DIM + f0 + sub * 4;
  const float* psb = ps + sub * 4;

  float a0[16], a1[16];
  #pragma unroll
  for (int e = 0; e < 16; ++e) { a0[e] = 0.f; a1[e] = 0.f; }

  // depth-1 pipelined k loop: cur consumed while next is in flight
  float4 c0 = *(const float4*)xr0;
  float4 c1 = *(const float4*)xr1;
  #pragma unroll 1
  for (int k = 0; k < 8; ++k) {
    float4 n0, n1;
    if (k < 7) {
      n0 = *(const float4*)&xr0[(k + 1) * 32];
      n1 = *(const float4*)&xr1[(k + 1) * 32];
    }
    uint2 pk0, pk1;
    pk0.x = (uint32_t)f2bf(c0.x) | ((uint32_t)f2bf(c0.y) << 16);
    pk0.y = (uint32_t)f2bf(c0.z) | ((uint32_t)f2bf(c0.w) << 16);
    pk1.x = (uint32_t)f2bf(c1.x) | ((uint32_t)f2bf(c1.y) << 16);
    pk1.y = (uint32_t)f2bf(c1.z) | ((uint32_t)f2bf(c1.w) << 16);
    *(uint2*)&xw0[k * 32] = pk0;
    *(uint2*)&xw1[k * 32] = pk1;
    #pragma unroll
    for (int e = 0; e < 16; ++e) {
      float4 pv = *(const float4*)&psb[e * 256 + k * 32];
      a0[e] += c0.x * pv.x; a0[e] += c0.y * pv.y;
      a0[e] += c0.z * pv.z; a0[e] += c0.w * pv.w;
      a1[e] += c1.x * pv.x; a1[e] += c1.y * pv.y;
      a1[e] += c1.z * pv.z; a1[e] += c1.w * pv.w;
    }
    c0 = n0; c1 = n1;
  }

  #pragma unroll
  for (int m = 1; m <= 4; m <<= 1) {
    #pragma unroll
    for (int e = 0; e < 16; ++e) {
      a0[e] += __shfl_xor(a0[e], m, 64);
      a1[e] += __shfl_xor(a1[e], m, 64);
    }
  }

  if (sub < 4) {
    partials4[((size_t)c * 4 + sub) * T_TOKENS + r0] =
        make_float4(a0[sub * 4], a0[sub * 4 + 1], a0[sub * 4 + 2], a0[sub * 4 + 3]);
    partials4[((size_t)c * 4 + sub) * T_TOKENS + r1] =
        make_float4(a1[sub * 4], a1[sub * 4 + 1], a1[sub * 4 + 2], a1[sub * 4 + 3]);
  }
}

// ---------------------------------------------------------------------------
// K2: gemm_xa composite: 64x64 tile, XCD-swizzled grid, 2 blocks/CU.
// (a) first K-tile pre-staged BEFORE the routing prologue (latency hides
//     under routing compute); (b) routing prologue spread across all 4 waves
//     (lanes<16, 16 tokens each) so no wave gates the block start;
// (c) ping-pong BK=64 double-buffer (stage next-half -> compute current),
//     so each stage's HBM/L3 latency hides under the previous COMP.
// Numerics (fp64 routing, MFMA order, epilogue) R0-exact.
// ---------------------------------------------------------------------------
__global__ __launch_bounds__(256) void gemm_xa(
    const uint16_t* __restrict__ xb, const uint16_t* __restrict__ Ab,
    const float4* __restrict__ partials4, const float* __restrict__ scaling,
    const int* __restrict__ topk, uint16_t* __restrict__ wb) {
  __shared__ uint16_t S[16384];   // 32 KB: X ping/pong + A ping/pong
  __shared__ float coeffL[64 * 17];
  uint16_t* X0 = S;
  uint16_t* X1 = S + 4096;
  uint16_t* A0 = S + 8192;
  uint16_t* A1 = S + 12288;
  const int tid  = threadIdx.x;
  const int b    = blockIdx.x;                       // 512 blocks
  const int m_idx = (b & 7) + ((b >> 5) << 3);       // 0..127 (same-XCD share m)
  const int n_idx = (b >> 3) & 3;                    // 0..3
  const int m0 = m_idx * 64, n0 = n_idx * 64;
  const int lane = tid & 63;
  const int wid  = tid >> 6;
  const int wm   = (wid >> 1) * 32;
  const int wn   = (wid & 1) * 32;
  const int quad = lane >> 4;
  const int cl   = lane & 15;

  // staging addresses (pre-swizzled global source, linear LDS dest)
  const int G0 = wid * 64 + lane;
  const int G1 = G0 + 256;
  const int r0 = G0 >> 3, g0 = (G0 & 7) ^ (r0 & 7);
  const int r1 = G1 >> 3, g1 = (G1 & 7) ^ (r1 & 7);
  const uint16_t* xs0 = xb + (size_t)(m0 + r0) * F_DIM + g0 * 8;
  const uint16_t* xs1 = xb + (size_t)(m0 + r1) * F_DIM + g1 * 8;
  const uint16_t* as0 = Ab + (size_t)(n0 + r0) * F_DIM + g0 * 8;
  const uint16_t* as1 = Ab + (size_t)(n0 + r1) * F_DIM + g1 * 8;
  const int d0 = wid * 512;
  const int d1 = wid * 512 + 2048;

  const int ma0 = wm + cl, ma1 = wm + 16 + cl;
  const int nb0 = wn + cl, nb1 = wn + 16 + cl;

#define STAGE_XA(Xb_, Ab_, kk) do {       \
    g2lds16(xs0 + (kk), (Xb_) + d0);      \
    g2lds16(xs1 + (kk), (Xb_) + d1);      \
    g2lds16(as0 + (kk), (Ab_) + d0);      \
    g2lds16(as1 + (kk), (Ab_) + d1);      \
  } while (0)

#define COMP_XA(Xb_, Ab_) do {                                                            \
    _Pragma("unroll")                                                                     \
    for (int ks = 0; ks < 2; ++ks) {                                                      \
      const int gk = ks * 4 + quad;                                                       \
      v8s fa0 = *(v8s*)&(Xb_)[(ma0 * 8 + (gk ^ (ma0 & 7))) * 8];                          \
      v8s fa1 = *(v8s*)&(Xb_)[(ma1 * 8 + (gk ^ (ma1 & 7))) * 8];                          \
      v8s fb0 = *(v8s*)&(Ab_)[(nb0 * 8 + (gk ^ (nb0 & 7))) * 8];                          \
      v8s fb1 = *(v8s*)&(Ab_)[(nb1 * 8 + (gk ^ (nb1 & 7))) * 8];                          \
      acc[0][0] = __builtin_amdgcn_mfma_f32_16x16x32_bf16(fa0, fb0, acc[0][0], 0, 0, 0);  \
      acc[0][1] = __builtin_amdgcn_mfma_f32_16x16x32_bf16(fa0, fb1, acc[0][1], 0, 0, 0);  \
      acc[1][0] = __builtin_amdgcn_mfma_f32_16x16x32_bf16(fa1, fb0, acc[1][0], 0, 0, 0);  \
      acc[1][1] = __builtin_amdgcn_mfma_f32_16x16x32_bf16(fa1, fb1, acc[1][1], 0, 0, 0);  \
    }                                                                                     \
  } while (0)

  v4f acc[2][2];
  #pragma unroll
  for (int i = 0; i < 2; i++)
    #pragma unroll
    for (int j = 0; j < 2; j++) acc[i][j] = (v4f){0.f, 0.f, 0.f, 0.f};

  // (a) pre-stage first 64-col half-tile; its latency hides under routing
  STAGE_XA(X0, A0, 0);

  // (b) routing prologue spread over 4 waves: 16 tokens each, lanes<16
  if (lane < 16) {
    const int tk = wid * 16 + cl;     // 0..63
    const int t  = m0 + tk;
    double s[16];
    #pragma unroll
    for (int e = 0; e < 16; ++e) s[e] = 0.0;
    for (int c = 0; c < 8; ++c) {
      #pragma unroll
      for (int e4 = 0; e4 < 4; ++e4) {
        float4 p = partials4[((size_t)c * 4 + e4) * T_TOKENS + t];
        s[e4 * 4]     += (double)p.x;
        s[e4 * 4 + 1] += (double)p.y;
        s[e4 * 4 + 2] += (double)p.z;
        s[e4 * 4 + 3] += (double)p.w;
      }
    }
    double v[16];
    #pragma unroll
    for (int e = 0; e < 16; ++e) v[e] = fabs(s[e]);
    int k = topk[0];
    if (k > 16) k = 16;
    if (k < 1)  k = 1;
    unsigned mask = 0;
    double mx = 0.0;
    float ssum = 0.f;
    for (int i = 0; i < k; ++i) {
      double bv = -1.0; int bj = 0;
      #pragma unroll
      for (int j = 0; j < 16; ++j) {
        bool ok = !((mask >> j) & 1u) && (v[j] > bv);
        bv = ok ? v[j] : bv;
        bj = ok ? j  : bj;
      }
      mask |= 1u << bj;
      if (i == 0) mx = bv;
      ssum += expf((float)(bv - mx));
    }
    const float sc = scaling[0];
    #pragma unroll
    for (int j = 0; j < 16; ++j)
      coeffL[tk * 17 + j] = ((mask >> j) & 1u)
          ? expf((float)(v[j] - mx)) / ssum * sc : 0.f;
  }

  // (c) ping-pong K loop: 16 x (two 64-col sub-steps)
  for (int k0 = 0; k0 < F_DIM; k0 += 128) {
    __syncthreads();                       // drains stage of X0/A0 (cols k0)
    STAGE_XA(X1, A1, k0 + 64);             // prefetch odd half
    COMP_XA(X0, A0);
    __syncthreads();                       // drains X1/A1; X0 reads done
    if (k0 + 128 < F_DIM) STAGE_XA(X0, A0, k0 + 128);   // prefetch next even
    COMP_XA(X1, A1);
  }

  // epilogue: coeff fold + bf16 pack via LDS bounce, 128B-contiguous stores
  __syncthreads();
  uint16_t* tile = S;   // stride 72
  #pragma unroll
  for (int mi = 0; mi < 2; mi++)
    #pragma unroll
    for (int ni = 0; ni < 2; ni++) {
      const int nl = wn + ni * 16 + cl;
      const int eidx = (n0 + nl) >> 4;
      #pragma unroll
      for (int reg = 0; reg < 4; reg++) {
        const int tl = wm + mi * 16 + quad * 4 + reg;
        float wv = acc[mi][ni][reg] * coeffL[tl * 17 + eidx];
        tile[tl * 72 + nl] = f2bf(wv);
      }
    }
  __syncthreads();
  #pragma unroll
  for (int p = 0; p < 2; ++p) {
    const int row  = p * 32 + (tid >> 3);
    const int colg = (tid & 7) * 8;
    uint4 val = *(uint4*)&tile[row * 72 + colg];
    *(uint4*)&wb[(size_t)(m0 + row) * KDIM + n0 + colg] = val;
  }
#undef STAGE_XA
#undef COMP_XA
}

// ---------------------------------------------------------------------------
// K3: gemm_wb (R0-exact), 64x256 tile (acc[2][8]/wave), BK=64 (4 iters),
// XCD-swizzled, two-pass fp32 LDS-bounce epilogue with 1KB-contiguous stores.
// ---------------------------------------------------------------------------
__global__ __launch_bounds__(256) void gemm_wb(
    const uint16_t* __restrict__ wbuf, const uint16_t* __restrict__ Bb,
    float* __restrict__ out) {
  __shared__ uint16_t S[20480];   // 40 KB: Ws 8 KB + Bs 32 KB
  uint16_t* Ws = S;               // 64 rows x 8 granules
  uint16_t* Bs = S + 4096;        // 256 rows x 8 granules
  const int tid  = threadIdx.x;
  const int b    = blockIdx.x;                       // 1024 blocks
  const int m_idx = (b & 7) + ((b >> 6) << 3);       // 0..127
  const int n_idx = (b >> 3) & 7;                    // 0..7
  const int m0 = m_idx * 64;
  const int n0 = n_idx * 256;
  const int lane = tid & 63;
  const int wid  = tid >> 6;
  const int wm   = (wid >> 1) * 32;
  const int wn   = (wid & 1) * 128;
  const int quad = lane >> 4;
  const int cl   = lane & 15;

  const int GW0 = wid * 64 + lane;
  const int GW1 = GW0 + 256;
  const int wr0 = GW0 >> 3, wg0 = (GW0 & 7) ^ (wr0 & 7);
  const int wr1 = GW1 >> 3, wg1 = (GW1 & 7) ^ (wr1 & 7);
  const uint16_t* wsrc0 = wbuf + (size_t)(m0 + wr0) * KDIM + wg0 * 8;
  const uint16_t* wsrc1 = wbuf + (size_t)(m0 + wr1) * KDIM + wg1 * 8;

  const uint16_t* bsrc[8];
  #pragma unroll
  for (int p = 0; p < 8; ++p) {
    const int G = p * 256 + wid * 64 + lane;
    const int r = G >> 3, g = (G & 7) ^ (r & 7);
    bsrc[p] = Bb + (size_t)(n0 + r) * KDIM + g * 8;
  }

  v4f acc[2][8];
  #pragma unroll
  for (int i = 0; i < 2; i++)
    #pragma unroll
    for (int j = 0; j < 8; j++) acc[i][j] = (v4f){0.f, 0.f, 0.f, 0.f};

  const int ma0 = wm + cl, ma1 = wm + 16 + cl;

  #pragma unroll
  for (int k0 = 0; k0 < KDIM; k0 += 64) {
    __syncthreads();
    g2lds16(wsrc0 + k0, Ws + wid * 512);
    g2lds16(wsrc1 + k0, Ws + wid * 512 + 2048);
    #pragma unroll
    for (int p = 0; p < 8; ++p)
      g2lds16(bsrc[p] + k0, Bs + (p * 256 + wid * 64) * 8);
    __syncthreads();
    #pragma unroll
    for (int ks = 0; ks < 2; ++ks) {
      const int gk = ks * 4 + quad;
      v8s fa0 = *(v8s*)&Ws[(ma0 * 8 + (gk ^ (ma0 & 7))) * 8];
      v8s fa1 = *(v8s*)&Ws[(ma1 * 8 + (gk ^ (ma1 & 7))) * 8];
      v8s fb[8];
      #pragma unroll
      for (int j = 0; j < 8; ++j) {
        const int nb = wn + j * 16 + cl;
        fb[j] = *(v8s*)&Bs[(nb * 8 + (gk ^ (nb & 7))) * 8];
      }
      #pragma unroll
      for (int j = 0; j < 8; ++j) {
        acc[0][j] = __builtin_amdgcn_mfma_f32_16x16x32_bf16(fa0, fb[j], acc[0][j], 0, 0, 0);
        acc[1][j] = __builtin_amdgcn_mfma_f32_16x16x32_bf16(fa1, fb[j], acc[1][j], 0, 0, 0);
      }
    }
  }

  float* ft = (float*)S;   // 32 x 260 floats
  #pragma unroll
  for (int h = 0; h < 2; ++h) {
    __syncthreads();
    if ((wid >> 1) == h) {
      #pragma unroll
      for (int mi = 0; mi < 2; mi++)
        #pragma unroll
        for (int j = 0; j < 8; j++) {
          const int col = wn + j * 16 + cl;
          #pragma unroll
          for (int reg = 0; reg < 4; reg++) {
            const int rl = mi * 16 + quad * 4 + reg;
            ft[rl * 260 + col] = acc[mi][j][reg];
          }
        }
    }
    __syncthreads();
    #pragma unroll
    for (int p = 0; p < 8; ++p) {
      const int f4  = p * 256 + tid;
      const int row = f4 >> 6;
      const int c4  = f4 & 63;
      float4 v = *(float4*)&ft[row * 260 + c4 * 4];
      *(float4*)&out[(size_t)(m0 + h * 32 + row) * O_DIM + n0 + c4 * 4] = v;
    }
  }
}

extern "C" void kernel_launch(void* const* d_in, const int* in_sizes, int n_in,
                              void* d_out, int out_size, void* d_ws, size_t ws_size,
                              hipStream_t stream) {
  (void)in_sizes; (void)n_in; (void)out_size; (void)ws_size;
  const float* x       = (const float*)d_in[0];
  const float* P       = (const float*)d_in[1];
  const float* A       = (const float*)d_in[2];
  const float* Bst     = (const float*)d_in[3];
  const float* scaling = (const float*)d_in[4];
  const int*   topk    = (const int*)d_in[5];
  float* out = (float*)d_out;

  char* ws = (char*)d_ws;
  uint16_t* xb     = (uint16_t*)(ws);                 // 33,554,432 B
  uint16_t* Ab     = (uint16_t*)(ws + 33554432);      //  1,048,576 B
  uint16_t* Bb     = (uint16_t*)(ws + 34603008);      //  1,048,576 B
  uint16_t* wbuf   = (uint16_t*)(ws + 35651584);      //  4,194,304 B
  float4*   parts  = (float4*)  (ws + 39845888);      //  4,194,304 B (no alias)

  // grid.x: 0..7 = route chunks (64 tokens/block), 8 = weight prep
  hipLaunchKernelGGL(route_stream, dim3(9, 128), dim3(256), 0, stream,
                     x, P, A, Bst, xb, parts, Ab, Bb);
  hipLaunchKernelGGL(gemm_xa, dim3(512), dim3(256), 0, stream,
                     xb, Ab, parts, scaling, topk, wbuf);
  hipLaunchKernelGGL(gemm_wb, dim3(1024), dim3(256), 0, stream, wbuf, Bb, out);
}

// Round 10
// 168.871 us; speedup vs baseline: 1.0177x; 1.0177x over previous
//
#include <hip/hip_runtime.h>
#include <hip/hip_bf16.h>
#include <stdint.h>

#define T_TOKENS 8192
#define F_DIM    2048
#define E_EXP    16
#define R_RANK   16
#define O_DIM    2048
#define KDIM     (E_EXP * R_RANK)   // 256

typedef short v8s __attribute__((ext_vector_type(8)));
typedef float v4f __attribute__((ext_vector_type(4)));

#define AS1 __attribute__((address_space(1)))
#define AS3 __attribute__((address_space(3)))

__device__ __forceinline__ uint16_t f2bf(float f) {
  uint32_t u = __builtin_bit_cast(uint32_t, f);
  u += 0x7fffu + ((u >> 16) & 1u);   // round-to-nearest-even
  return (uint16_t)(u >> 16);
}

// async global->LDS, 16B per lane; LDS dest = wave-uniform base + lane*16
__device__ __forceinline__ void g2lds16(const void* g, void* l) {
  __builtin_amdgcn_global_load_lds((const AS1 void*)g, (AS3 void*)l, 16, 0, 0);
}

// reg-stage one X granule: 8 fp32 from x -> bf16x8 (bit-identical to the old
// xb image: same f2bf, same granule address) -> one ds_write_b128.
__device__ __forceinline__ void stageX(const float* src, uint16_t* ldst) {
  float4 a = *(const float4*)src;
  float4 b = *(const float4*)(src + 4);
  uint4 pk;
  pk.x = (uint32_t)f2bf(a.x) | ((uint32_t)f2bf(a.y) << 16);
  pk.y = (uint32_t)f2bf(a.z) | ((uint32_t)f2bf(a.w) << 16);
  pk.z = (uint32_t)f2bf(b.x) | ((uint32_t)f2bf(b.y) << 16);
  pk.w = (uint32_t)f2bf(b.z) | ((uint32_t)f2bf(b.w) << 16);
  *(uint4*)ldst = pk;
}

// ---------------------------------------------------------------------------
// K1: route_stream v5 — R8's depth-1 pipeline MINUS the xb writes (xb is
// eliminated: gemm_xa now converts x on the fly). Pure: read x, sims FMA,
// butterfly reduce, write partials. Grid 9 x 128: c 0..7 route chunks,
// c == 8: weight prep (x-interleaved). Partials: [(c*4+e4)*8192 + t].
// ---------------------------------------------------------------------------
__global__ __launch_bounds__(256) void route_stream(
    const float* __restrict__ x, const float* __restrict__ P,
    const float* __restrict__ A, const float* __restrict__ Bst,
    float4* __restrict__ partials4,
    uint16_t* __restrict__ Ab, uint16_t* __restrict__ Bb) {
  __shared__ float ps[16 * 256];   // 16 KB, linear (g2lds dest)
  const int tid = threadIdx.x;
  const int c   = blockIdx.x;      // 0..7 route chunk; 8 = weight prep
  const int by  = blockIdx.y;      // 0..127

  if (c == 8) {
    const int base = by * 4096;
    #pragma unroll
    for (int p = 0; p < 16; ++p) {
      const int i = base + p * 256 + tid;
      Ab[i] = f2bf(A[i]);
      const int k = i & (KDIM - 1);
      const int o = i >> 8;
      Bb[i] = f2bf(Bst[((size_t)(k >> 4) * O_DIM + o) * R_RANK + (k & 15)]);
    }
    return;
  }

  const int f0 = c * 256;
  #pragma unroll
  for (int p = 0; p < 4; ++p) {
    const int G = p * 256 + tid;                  // 0..1023
    g2lds16(&P[(size_t)(G >> 6) * F_DIM + f0 + (G & 63) * 4],
            (char*)ps + (p * 256 + (tid >> 6) * 64) * 16);
  }
  __syncthreads();

  const int sub = tid & 7;         // 32-col slice: cols {sub*4 + k*32}
  const int tg  = tid >> 3;        // 0..31
  const int r0  = by * 64 + tg;    // token A
  const int r1  = r0 + 32;         // token B
  const float* xr0 = x + (size_t)r0 * F_DIM + f0 + sub * 4;
  const float* xr1 = x + (size_t)r1 * F_DIM + f0 + sub * 4;
  const float* psb = ps + sub * 4;

  float a0[16], a1[16];
  #pragma unroll
  for (int e = 0; e < 16; ++e) { a0[e] = 0.f; a1[e] = 0.f; }

  // depth-1 pipelined k loop: cur consumed while next is in flight
  float4 c0 = *(const float4*)xr0;
  float4 c1 = *(const float4*)xr1;
  #pragma unroll 1
  for (int k = 0; k < 8; ++k) {
    float4 n0, n1;
    if (k < 7) {
      n0 = *(const float4*)&xr0[(k + 1) * 32];
      n1 = *(const float4*)&xr1[(k + 1) * 32];
    }
    #pragma unroll
    for (int e = 0; e < 16; ++e) {
      float4 pv = *(const float4*)&psb[e * 256 + k * 32];
      a0[e] += c0.x * pv.x; a0[e] += c0.y * pv.y;
      a0[e] += c0.z * pv.z; a0[e] += c0.w * pv.w;
      a1[e] += c1.x * pv.x; a1[e] += c1.y * pv.y;
      a1[e] += c1.z * pv.z; a1[e] += c1.w * pv.w;
    }
    c0 = n0; c1 = n1;
  }

  #pragma unroll
  for (int m = 1; m <= 4; m <<= 1) {
    #pragma unroll
    for (int e = 0; e < 16; ++e) {
      a0[e] += __shfl_xor(a0[e], m, 64);
      a1[e] += __shfl_xor(a1[e], m, 64);
    }
  }

  if (sub < 4) {
    partials4[((size_t)c * 4 + sub) * T_TOKENS + r0] =
        make_float4(a0[sub * 4], a0[sub * 4 + 1], a0[sub * 4 + 2], a0[sub * 4 + 3]);
    partials4[((size_t)c * 4 + sub) * T_TOKENS + r1] =
        make_float4(a1[sub * 4], a1[sub * 4 + 1], a1[sub * 4 + 2], a1[sub * 4 + 3]);
  }
}

// ---------------------------------------------------------------------------
// K2: gemm_xa — R0-EXACT skeleton (grid, barriers, tid<64 fp64 prologue,
// COMP order, epilogue all unchanged). Only the X-staging path differs:
// instead of g2lds from precomputed xb, each thread reg-stages its granule
// straight from x fp32 (2 float4 loads + f2bf pack + ds_write_b128) to the
// SAME LDS address with the SAME bits. A-staging remains async g2lds (Ab).
// ---------------------------------------------------------------------------
__global__ __launch_bounds__(256) void gemm_xa(
    const float* __restrict__ x, const uint16_t* __restrict__ Ab,
    const float4* __restrict__ partials4, const float* __restrict__ scaling,
    const int* __restrict__ topk, uint16_t* __restrict__ wb) {
  __shared__ uint16_t S[16384];   // 32 KB staging
  __shared__ float coeffL[64 * 17];
  uint16_t* Xh[2] = { S,         S + 4096  };
  uint16_t* Ah[2] = { S + 8192,  S + 12288 };
  const int tid  = threadIdx.x;
  const int b    = blockIdx.x;                       // 512 blocks
  const int m_idx = (b & 7) + ((b >> 5) << 3);       // 0..127 (same-XCD share m)
  const int n_idx = (b >> 3) & 3;                    // 0..3
  const int m0 = m_idx * 64, n0 = n_idx * 64;
  const int lane = tid & 63;
  const int wid  = tid >> 6;
  const int wm   = (wid >> 1) * 32;
  const int wn   = (wid & 1) * 32;
  const int quad = lane >> 4;
  const int cl   = lane & 15;

  // ---- routing prologue: tokens m0..m0+63 (R0-exact fp64) ----
  if (tid < 64) {
    const int t = m0 + tid;
    double s[16];
    #pragma unroll
    for (int e = 0; e < 16; ++e) s[e] = 0.0;
    for (int c = 0; c < 8; ++c) {
      #pragma unroll
      for (int e4 = 0; e4 < 4; ++e4) {
        float4 p = partials4[((size_t)c * 4 + e4) * T_TOKENS + t];
        s[e4 * 4]     += (double)p.x;
        s[e4 * 4 + 1] += (double)p.y;
        s[e4 * 4 + 2] += (double)p.z;
        s[e4 * 4 + 3] += (double)p.w;
      }
    }
    double v[16];
    #pragma unroll
    for (int e = 0; e < 16; ++e) v[e] = fabs(s[e]);
    int k = topk[0];
    if (k > 16) k = 16;
    if (k < 1)  k = 1;
    unsigned mask = 0;
    double mx = 0.0;
    float ssum = 0.f;
    for (int i = 0; i < k; ++i) {
      double bv = -1.0; int bj = 0;
      #pragma unroll
      for (int j = 0; j < 16; ++j) {
        bool ok = !((mask >> j) & 1u) && (v[j] > bv);
        bv = ok ? v[j] : bv;
        bj = ok ? j  : bj;
      }
      mask |= 1u << bj;
      if (i == 0) mx = bv;
      ssum += expf((float)(bv - mx));
    }
    const float sc = scaling[0];
    #pragma unroll
    for (int j = 0; j < 16; ++j)
      coeffL[tid * 17 + j] = ((mask >> j) & 1u)
          ? expf((float)(v[j] - mx)) / ssum * sc : 0.f;
  }

  // ---- GEMM ----
  const int G0 = wid * 64 + lane;
  const int G1 = G0 + 256;
  const int r0 = G0 >> 3, g0 = (G0 & 7) ^ (r0 & 7);
  const int r1 = G1 >> 3, g1 = (G1 & 7) ^ (r1 & 7);
  const float* xs0f = x + (size_t)(m0 + r0) * F_DIM + g0 * 8;   // fp32 source
  const float* xs1f = x + (size_t)(m0 + r1) * F_DIM + g1 * 8;
  const uint16_t* as0 = Ab + (size_t)(n0 + r0) * F_DIM + g0 * 8;
  const uint16_t* as1 = Ab + (size_t)(n0 + r1) * F_DIM + g1 * 8;
  const int d0 = wid * 512;
  const int d1 = wid * 512 + 2048;

  const int ma0 = wm + cl, ma1 = wm + 16 + cl;
  const int nb0 = wn + cl, nb1 = wn + 16 + cl;

  v4f acc[2][2];
  #pragma unroll
  for (int i = 0; i < 2; i++)
    #pragma unroll
    for (int j = 0; j < 2; j++) acc[i][j] = (v4f){0.f, 0.f, 0.f, 0.f};

  for (int k0 = 0; k0 < F_DIM; k0 += 128) {
    __syncthreads();
    // A: async g2lds (issued first so loads fly under X conversion)
    g2lds16(as0 + k0,      Ah[0] + d0);
    g2lds16(as1 + k0,      Ah[0] + d1);
    g2lds16(as0 + k0 + 64, Ah[1] + d0);
    g2lds16(as1 + k0 + 64, Ah[1] + d1);
    // X: reg-stage from x fp32 -> identical bf16 LDS image as old xb path
    stageX(xs0f + k0,      Xh[0] + G0 * 8);
    stageX(xs1f + k0,      Xh[0] + G1 * 8);
    stageX(xs0f + k0 + 64, Xh[1] + G0 * 8);
    stageX(xs1f + k0 + 64, Xh[1] + G1 * 8);
    __syncthreads();
    #pragma unroll
    for (int h = 0; h < 2; ++h) {
      #pragma unroll
      for (int ks = 0; ks < 2; ++ks) {
        const int gk = ks * 4 + quad;
        v8s fa0 = *(v8s*)&Xh[h][(ma0 * 8 + (gk ^ (ma0 & 7))) * 8];
        v8s fa1 = *(v8s*)&Xh[h][(ma1 * 8 + (gk ^ (ma1 & 7))) * 8];
        v8s fb0 = *(v8s*)&Ah[h][(nb0 * 8 + (gk ^ (nb0 & 7))) * 8];
        v8s fb1 = *(v8s*)&Ah[h][(nb1 * 8 + (gk ^ (nb1 & 7))) * 8];
        acc[0][0] = __builtin_amdgcn_mfma_f32_16x16x32_bf16(fa0, fb0, acc[0][0], 0, 0, 0);
        acc[0][1] = __builtin_amdgcn_mfma_f32_16x16x32_bf16(fa0, fb1, acc[0][1], 0, 0, 0);
        acc[1][0] = __builtin_amdgcn_mfma_f32_16x16x32_bf16(fa1, fb0, acc[1][0], 0, 0, 0);
        acc[1][1] = __builtin_amdgcn_mfma_f32_16x16x32_bf16(fa1, fb1, acc[1][1], 0, 0, 0);
      }
    }
  }

  // epilogue: coeff fold + bf16 pack via LDS bounce, 128B-contiguous stores
  __syncthreads();
  uint16_t* tile = S;   // stride 72
  #pragma unroll
  for (int mi = 0; mi < 2; mi++)
    #pragma unroll
    for (int ni = 0; ni < 2; ni++) {
      const int nl = wn + ni * 16 + cl;
      const int eidx = (n0 + nl) >> 4;
      #pragma unroll
      for (int reg = 0; reg < 4; reg++) {
        const int tl = wm + mi * 16 + quad * 4 + reg;
        float wv = acc[mi][ni][reg] * coeffL[tl * 17 + eidx];
        tile[tl * 72 + nl] = f2bf(wv);
      }
    }
  __syncthreads();
  #pragma unroll
  for (int p = 0; p < 2; ++p) {
    const int row  = p * 32 + (tid >> 3);
    const int colg = (tid & 7) * 8;
    uint4 val = *(uint4*)&tile[row * 72 + colg];
    *(uint4*)&wb[(size_t)(m0 + row) * KDIM + n0 + colg] = val;
  }
}

// ---------------------------------------------------------------------------
// K3: gemm_wb (R0-exact), 64x256 tile (acc[2][8]/wave), BK=64 (4 iters),
// XCD-swizzled, two-pass fp32 LDS-bounce epilogue with 1KB-contiguous stores.
// ---------------------------------------------------------------------------
__global__ __launch_bounds__(256) void gemm_wb(
    const uint16_t* __restrict__ wbuf, const uint16_t* __restrict__ Bb,
    float* __restrict__ out) {
  __shared__ uint16_t S[20480];   // 40 KB: Ws 8 KB + Bs 32 KB
  uint16_t* Ws = S;               // 64 rows x 8 granules
  uint16_t* Bs = S + 4096;        // 256 rows x 8 granules
  const int tid  = threadIdx.x;
  const int b    = blockIdx.x;                       // 1024 blocks
  const int m_idx = (b & 7) + ((b >> 6) << 3);       // 0..127
  const int n_idx = (b >> 3) & 7;                    // 0..7
  const int m0 = m_idx * 64;
  const int n0 = n_idx * 256;
  const int lane = tid & 63;
  const int wid  = tid >> 6;
  const int wm   = (wid >> 1) * 32;
  const int wn   = (wid & 1) * 128;
  const int quad = lane >> 4;
  const int cl   = lane & 15;

  const int GW0 = wid * 64 + lane;
  const int GW1 = GW0 + 256;
  const int wr0 = GW0 >> 3, wg0 = (GW0 & 7) ^ (wr0 & 7);
  const int wr1 = GW1 >> 3, wg1 = (GW1 & 7) ^ (wr1 & 7);
  const uint16_t* wsrc0 = wbuf + (size_t)(m0 + wr0) * KDIM + wg0 * 8;
  const uint16_t* wsrc1 = wbuf + (size_t)(m0 + wr1) * KDIM + wg1 * 8;

  const uint16_t* bsrc[8];
  #pragma unroll
  for (int p = 0; p < 8; ++p) {
    const int G = p * 256 + wid * 64 + lane;
    const int r = G >> 3, g = (G & 7) ^ (r & 7);
    bsrc[p] = Bb + (size_t)(n0 + r) * KDIM + g * 8;
  }

  v4f acc[2][8];
  #pragma unroll
  for (int i = 0; i < 2; i++)
    #pragma unroll
    for (int j = 0; j < 8; j++) acc[i][j] = (v4f){0.f, 0.f, 0.f, 0.f};

  const int ma0 = wm + cl, ma1 = wm + 16 + cl;

  #pragma unroll
  for (int k0 = 0; k0 < KDIM; k0 += 64) {
    __syncthreads();
    g2lds16(wsrc0 + k0, Ws + wid * 512);
    g2lds16(wsrc1 + k0, Ws + wid * 512 + 2048);
    #pragma unroll
    for (int p = 0; p < 8; ++p)
      g2lds16(bsrc[p] + k0, Bs + (p * 256 + wid * 64) * 8);
    __syncthreads();
    #pragma unroll
    for (int ks = 0; ks < 2; ++ks) {
      const int gk = ks * 4 + quad;
      v8s fa0 = *(v8s*)&Ws[(ma0 * 8 + (gk ^ (ma0 & 7))) * 8];
      v8s fa1 = *(v8s*)&Ws[(ma1 * 8 + (gk ^ (ma1 & 7))) * 8];
      v8s fb[8];
      #pragma unroll
      for (int j = 0; j < 8; ++j) {
        const int nb = wn + j * 16 + cl;
        fb[j] = *(v8s*)&Bs[(nb * 8 + (gk ^ (nb & 7))) * 8];
      }
      #pragma unroll
      for (int j = 0; j < 8; ++j) {
        acc[0][j] = __builtin_amdgcn_mfma_f32_16x16x32_bf16(fa0, fb[j], acc[0][j], 0, 0, 0);
        acc[1][j] = __builtin_amdgcn_mfma_f32_16x16x32_bf16(fa1, fb[j], acc[1][j], 0, 0, 0);
      }
    }
  }

  float* ft = (float*)S;   // 32 x 260 floats
  #pragma unroll
  for (int h = 0; h < 2; ++h) {
    __syncthreads();
    if ((wid >> 1) == h) {
      #pragma unroll
      for (int mi = 0; mi < 2; mi++)
        #pragma unroll
        for (int j = 0; j < 8; j++) {
          const int col = wn + j * 16 + cl;
          #pragma unroll
          for (int reg = 0; reg < 4; reg++) {
            const int rl = mi * 16 + quad * 4 + reg;
            ft[rl * 260 + col] = acc[mi][j][reg];
          }
        }
    }
    __syncthreads();
    #pragma unroll
    for (int p = 0; p < 8; ++p) {
      const int f4  = p * 256 + tid;
      const int row = f4 >> 6;
      const int c4  = f4 & 63;
      float4 v = *(float4*)&ft[row * 260 + c4 * 4];
      *(float4*)&out[(size_t)(m0 + h * 32 + row) * O_DIM + n0 + c4 * 4] = v;
    }
  }
}

extern "C" void kernel_launch(void* const* d_in, const int* in_sizes, int n_in,
                              void* d_out, int out_size, void* d_ws, size_t ws_size,
                              hipStream_t stream) {
  (void)in_sizes; (void)n_in; (void)out_size; (void)ws_size;
  const float* x       = (const float*)d_in[0];
  const float* P       = (const float*)d_in[1];
  const float* A       = (const float*)d_in[2];
  const float* Bst     = (const float*)d_in[3];
  const float* scaling = (const float*)d_in[4];
  const int*   topk    = (const int*)d_in[5];
  float* out = (float*)d_out;

  char* ws = (char*)d_ws;
  uint16_t* Ab   = (uint16_t*)(ws);               // 1,048,576 B
  uint16_t* Bb   = (uint16_t*)(ws + 1048576);     // 1,048,576 B
  uint16_t* wbuf = (uint16_t*)(ws + 2097152);     // 4,194,304 B
  float4*  parts = (float4*)  (ws + 6291456);     // 4,194,304 B (no alias)

  // grid.x: 0..7 = route chunks (64 tokens/block), 8 = weight prep
  hipLaunchKernelGGL(route_stream, dim3(9, 128), dim3(256), 0, stream,
                     x, P, A, Bst, parts, Ab, Bb);
  hipLaunchKernelGGL(gemm_xa, dim3(512), dim3(256), 0, stream,
                     x, Ab, parts, scaling, topk, wbuf);
  hipLaunchKernelGGL(gemm_wb, dim3(1024), dim3(256), 0, stream, wbuf, Bb, out);
}

// Round 11
// 164.087 us; speedup vs baseline: 1.0473x; 1.0292x over previous
//
#include <hip/hip_runtime.h>
#include <hip/hip_bf16.h>
#include <stdint.h>

#define T_TOKENS 8192
#define F_DIM    2048
#define E_EXP    16
#define R_RANK   16
#define O_DIM    2048
#define KDIM     (E_EXP * R_RANK)   // 256

typedef short v8s __attribute__((ext_vector_type(8)));
typedef float v4f __attribute__((ext_vector_type(4)));

#define AS1 __attribute__((address_space(1)))
#define AS3 __attribute__((address_space(3)))

__device__ __forceinline__ uint16_t f2bf(float f) {
  uint32_t u = __builtin_bit_cast(uint32_t, f);
  u += 0x7fffu + ((u >> 16) & 1u);   // round-to-nearest-even
  return (uint16_t)(u >> 16);
}

// async global->LDS, 16B per lane; LDS dest = wave-uniform base + lane*16
__device__ __forceinline__ void g2lds16(const void* g, void* l) {
  __builtin_amdgcn_global_load_lds((const AS1 void*)g, (AS3 void*)l, 16, 0, 0);
}

// ---------------------------------------------------------------------------
// K1: route_stream (R7-exact: best measured total, 163.2 us). 2-token
// register tiling. Grid 9 x 128: c 0..7 route chunks (256 cols, 64 tokens),
// c == 8: weight prep (x-interleaved in dispatch order).
// Partials layout: float4 partials4[(c*4+e4)*8192 + t].
// ---------------------------------------------------------------------------
__global__ __launch_bounds__(256) void route_stream(
    const float* __restrict__ x, const float* __restrict__ P,
    const float* __restrict__ A, const float* __restrict__ Bst,
    uint16_t* __restrict__ xb, float4* __restrict__ partials4,
    uint16_t* __restrict__ Ab, uint16_t* __restrict__ Bb) {
  __shared__ float ps[16 * 256];   // 16 KB, linear (g2lds dest)
  const int tid = threadIdx.x;
  const int c   = blockIdx.x;      // 0..7 route chunk; 8 = weight prep
  const int by  = blockIdx.y;      // 0..127

  if (c == 8) {
    const int base = by * 4096;
    #pragma unroll
    for (int p = 0; p < 16; ++p) {
      const int i = base + p * 256 + tid;
      Ab[i] = f2bf(A[i]);
      const int k = i & (KDIM - 1);
      const int o = i >> 8;
      Bb[i] = f2bf(Bst[((size_t)(k >> 4) * O_DIM + o) * R_RANK + (k & 15)]);
    }
    return;
  }

  const int f0 = c * 256;
  #pragma unroll
  for (int p = 0; p < 4; ++p) {
    const int G = p * 256 + tid;                  // 0..1023
    g2lds16(&P[(size_t)(G >> 6) * F_DIM + f0 + (G & 63) * 4],
            (char*)ps + (p * 256 + (tid >> 6) * 64) * 16);
  }
  __syncthreads();

  const int sub = tid & 7;         // 32-col slice: cols {sub*4 + k*32}
  const int tg  = tid >> 3;        // 0..31
  const int r0  = by * 64 + tg;    // token A
  const int r1  = r0 + 32;         // token B
  const float* xr0 = x  + (size_t)r0 * F_DIM + f0;
  const float* xr1 = x  + (size_t)r1 * F_DIM + f0;
  uint16_t*    xw0 = xb + (size_t)r0 * F_DIM + f0;
  uint16_t*    xw1 = xb + (size_t)r1 * F_DIM + f0;

  float a0[16], a1[16];
  #pragma unroll
  for (int e = 0; e < 16; ++e) { a0[e] = 0.f; a1[e] = 0.f; }

  // load both tokens' slices up-front (16 outstanding loads / thread)
  float4 v0[8], v1[8];
  #pragma unroll
  for (int k = 0; k < 8; ++k)
    v0[k] = *(const float4*)&xr0[sub * 4 + k * 32];
  #pragma unroll
  for (int k = 0; k < 8; ++k)
    v1[k] = *(const float4*)&xr1[sub * 4 + k * 32];

  // pack + store bf16 (both tokens)
  #pragma unroll
  for (int k = 0; k < 8; ++k) {
    uint2 pk0, pk1;
    pk0.x = (uint32_t)f2bf(v0[k].x) | ((uint32_t)f2bf(v0[k].y) << 16);
    pk0.y = (uint32_t)f2bf(v0[k].z) | ((uint32_t)f2bf(v0[k].w) << 16);
    pk1.x = (uint32_t)f2bf(v1[k].x) | ((uint32_t)f2bf(v1[k].y) << 16);
    pk1.y = (uint32_t)f2bf(v1[k].z) | ((uint32_t)f2bf(v1[k].w) << 16);
    *(uint2*)&xw0[sub * 4 + k * 32] = pk0;
    *(uint2*)&xw1[sub * 4 + k * 32] = pk1;
  }

  // sims FMA: one ds_read_b128 serves both tokens (8 FMAs / read)
  #pragma unroll
  for (int k = 0; k < 8; ++k) {
    const int col = sub * 4 + k * 32;
    #pragma unroll
    for (int e = 0; e < 16; ++e) {
      float4 pv = *(float4*)&ps[e * 256 + col];
      a0[e] += v0[k].x * pv.x; a0[e] += v0[k].y * pv.y;
      a0[e] += v0[k].z * pv.z; a0[e] += v0[k].w * pv.w;
      a1[e] += v1[k].x * pv.x; a1[e] += v1[k].y * pv.y;
      a1[e] += v1[k].z * pv.z; a1[e] += v1[k].w * pv.w;
    }
  }

  // reduce across the 8 sub-lanes: 3 butterfly rounds per token
  #pragma unroll
  for (int m = 1; m <= 4; m <<= 1) {
    #pragma unroll
    for (int e = 0; e < 16; ++e) {
      a0[e] += __shfl_xor(a0[e], m, 64);
      a1[e] += __shfl_xor(a1[e], m, 64);
    }
  }

  if (sub < 4) {
    partials4[((size_t)c * 4 + sub) * T_TOKENS + r0] =
        make_float4(a0[sub * 4], a0[sub * 4 + 1], a0[sub * 4 + 2], a0[sub * 4 + 3]);
    partials4[((size_t)c * 4 + sub) * T_TOKENS + r1] =
        make_float4(a1[sub * 4], a1[sub * 4 + 1], a1[sub * 4 + 2], a1[sub * 4 + 3]);
  }
}

// ---------------------------------------------------------------------------
// K2: gemm_xa (R0-exact), 64x64 tile BK=128, XCD-swizzled linear grid, topk
// folded into prologue (tid<64: fp64 cross-chunk sum + topk + softmax).
// 512 blocks = 2 blocks/CU (cross-block overlap covers barrier drains).
// ---------------------------------------------------------------------------
__global__ __launch_bounds__(256) void gemm_xa(
    const uint16_t* __restrict__ xb, const uint16_t* __restrict__ Ab,
    const float4* __restrict__ partials4, const float* __restrict__ scaling,
    const int* __restrict__ topk, uint16_t* __restrict__ wb) {
  __shared__ uint16_t S[16384];   // 32 KB staging
  __shared__ float coeffL[64 * 17];
  uint16_t* Xh[2] = { S,         S + 4096  };
  uint16_t* Ah[2] = { S + 8192,  S + 12288 };
  const int tid  = threadIdx.x;
  const int b    = blockIdx.x;                       // 512 blocks
  const int m_idx = (b & 7) + ((b >> 5) << 3);       // 0..127 (same-XCD share m)
  const int n_idx = (b >> 3) & 3;                    // 0..3
  const int m0 = m_idx * 64, n0 = n_idx * 64;
  const int lane = tid & 63;
  const int wid  = tid >> 6;
  const int wm   = (wid >> 1) * 32;
  const int wn   = (wid & 1) * 32;
  const int quad = lane >> 4;
  const int cl   = lane & 15;

  // ---- routing prologue: tokens m0..m0+63 ----
  if (tid < 64) {
    const int t = m0 + tid;
    double s[16];
    #pragma unroll
    for (int e = 0; e < 16; ++e) s[e] = 0.0;
    for (int c = 0; c < 8; ++c) {
      #pragma unroll
      for (int e4 = 0; e4 < 4; ++e4) {
        float4 p = partials4[((size_t)c * 4 + e4) * T_TOKENS + t];
        s[e4 * 4]     += (double)p.x;
        s[e4 * 4 + 1] += (double)p.y;
        s[e4 * 4 + 2] += (double)p.z;
        s[e4 * 4 + 3] += (double)p.w;
      }
    }
    double v[16];
    #pragma unroll
    for (int e = 0; e < 16; ++e) v[e] = fabs(s[e]);
    int k = topk[0];
    if (k > 16) k = 16;
    if (k < 1)  k = 1;
    unsigned mask = 0;
    double mx = 0.0;
    float ssum = 0.f;
    for (int i = 0; i < k; ++i) {
      double bv = -1.0; int bj = 0;
      #pragma unroll
      for (int j = 0; j < 16; ++j) {
        bool ok = !((mask >> j) & 1u) && (v[j] > bv);
        bv = ok ? v[j] : bv;
        bj = ok ? j  : bj;
      }
      mask |= 1u << bj;
      if (i == 0) mx = bv;
      ssum += expf((float)(bv - mx));
    }
    const float sc = scaling[0];
    #pragma unroll
    for (int j = 0; j < 16; ++j)
      coeffL[tid * 17 + j] = ((mask >> j) & 1u)
          ? expf((float)(v[j] - mx)) / ssum * sc : 0.f;
  }

  // ---- GEMM ----
  const int G0 = wid * 64 + lane;
  const int G1 = G0 + 256;
  const int r0 = G0 >> 3, g0 = (G0 & 7) ^ (r0 & 7);
  const int r1 = G1 >> 3, g1 = (G1 & 7) ^ (r1 & 7);
  const uint16_t* xs0 = xb + (size_t)(m0 + r0) * F_DIM + g0 * 8;
  const uint16_t* xs1 = xb + (size_t)(m0 + r1) * F_DIM + g1 * 8;
  const uint16_t* as0 = Ab + (size_t)(n0 + r0) * F_DIM + g0 * 8;
  const uint16_t* as1 = Ab + (size_t)(n0 + r1) * F_DIM + g1 * 8;
  const int d0 = wid * 512;
  const int d1 = wid * 512 + 2048;

  const int ma0 = wm + cl, ma1 = wm + 16 + cl;
  const int nb0 = wn + cl, nb1 = wn + 16 + cl;

  v4f acc[2][2];
  #pragma unroll
  for (int i = 0; i < 2; i++)
    #pragma unroll
    for (int j = 0; j < 2; j++) acc[i][j] = (v4f){0.f, 0.f, 0.f, 0.f};

  for (int k0 = 0; k0 < F_DIM; k0 += 128) {
    __syncthreads();
    g2lds16(xs0 + k0,      Xh[0] + d0);
    g2lds16(xs1 + k0,      Xh[0] + d1);
    g2lds16(as0 + k0,      Ah[0] + d0);
    g2lds16(as1 + k0,      Ah[0] + d1);
    g2lds16(xs0 + k0 + 64, Xh[1] + d0);
    g2lds16(xs1 + k0 + 64, Xh[1] + d1);
    g2lds16(as0 + k0 + 64, Ah[1] + d0);
    g2lds16(as1 + k0 + 64, Ah[1] + d1);
    __syncthreads();
    #pragma unroll
    for (int h = 0; h < 2; ++h) {
      #pragma unroll
      for (int ks = 0; ks < 2; ++ks) {
        const int gk = ks * 4 + quad;
        v8s fa0 = *(v8s*)&Xh[h][(ma0 * 8 + (gk ^ (ma0 & 7))) * 8];
        v8s fa1 = *(v8s*)&Xh[h][(ma1 * 8 + (gk ^ (ma1 & 7))) * 8];
        v8s fb0 = *(v8s*)&Ah[h][(nb0 * 8 + (gk ^ (nb0 & 7))) * 8];
        v8s fb1 = *(v8s*)&Ah[h][(nb1 * 8 + (gk ^ (nb1 & 7))) * 8];
        acc[0][0] = __builtin_amdgcn_mfma_f32_16x16x32_bf16(fa0, fb0, acc[0][0], 0, 0, 0);
        acc[0][1] = __builtin_amdgcn_mfma_f32_16x16x32_bf16(fa0, fb1, acc[0][1], 0, 0, 0);
        acc[1][0] = __builtin_amdgcn_mfma_f32_16x16x32_bf16(fa1, fb0, acc[1][0], 0, 0, 0);
        acc[1][1] = __builtin_amdgcn_mfma_f32_16x16x32_bf16(fa1, fb1, acc[1][1], 0, 0, 0);
      }
    }
  }

  // epilogue: coeff fold + bf16 pack via LDS bounce, 128B-contiguous stores
  __syncthreads();
  uint16_t* tile = S;   // stride 72
  #pragma unroll
  for (int mi = 0; mi < 2; mi++)
    #pragma unroll
    for (int ni = 0; ni < 2; ni++) {
      const int nl = wn + ni * 16 + cl;
      const int eidx = (n0 + nl) >> 4;
      #pragma unroll
      for (int reg = 0; reg < 4; reg++) {
        const int tl = wm + mi * 16 + quad * 4 + reg;
        float wv = acc[mi][ni][reg] * coeffL[tl * 17 + eidx];
        tile[tl * 72 + nl] = f2bf(wv);
      }
    }
  __syncthreads();
  #pragma unroll
  for (int p = 0; p < 2; ++p) {
    const int row  = p * 32 + (tid >> 3);
    const int colg = (tid & 7) * 8;
    uint4 val = *(uint4*)&tile[row * 72 + colg];
    *(uint4*)&wb[(size_t)(m0 + row) * KDIM + n0 + colg] = val;
  }
}

// ---------------------------------------------------------------------------
// K3: gemm_wb (R0-exact), 64x256 tile (acc[2][8]/wave), BK=64 (4 iters),
// XCD-swizzled, two-pass fp32 LDS-bounce epilogue with 1KB-contiguous stores.
// ---------------------------------------------------------------------------
__global__ __launch_bounds__(256) void gemm_wb(
    const uint16_t* __restrict__ wbuf, const uint16_t* __restrict__ Bb,
    float* __restrict__ out) {
  __shared__ uint16_t S[20480];   // 40 KB: Ws 8 KB + Bs 32 KB
  uint16_t* Ws = S;               // 64 rows x 8 granules
  uint16_t* Bs = S + 4096;        // 256 rows x 8 granules
  const int tid  = threadIdx.x;
  const int b    = blockIdx.x;                       // 1024 blocks
  const int m_idx = (b & 7) + ((b >> 6) << 3);       // 0..127
  const int n_idx = (b >> 3) & 7;                    // 0..7
  const int m0 = m_idx * 64;
  const int n0 = n_idx * 256;
  const int lane = tid & 63;
  const int wid  = tid >> 6;
  const int wm   = (wid >> 1) * 32;
  const int wn   = (wid & 1) * 128;
  const int quad = lane >> 4;
  const int cl   = lane & 15;

  const int GW0 = wid * 64 + lane;
  const int GW1 = GW0 + 256;
  const int wr0 = GW0 >> 3, wg0 = (GW0 & 7) ^ (wr0 & 7);
  const int wr1 = GW1 >> 3, wg1 = (GW1 & 7) ^ (wr1 & 7);
  const uint16_t* wsrc0 = wbuf + (size_t)(m0 + wr0) * KDIM + wg0 * 8;
  const uint16_t* wsrc1 = wbuf + (size_t)(m0 + wr1) * KDIM + wg1 * 8;

  const uint16_t* bsrc[8];
  #pragma unroll
  for (int p = 0; p < 8; ++p) {
    const int G = p * 256 + wid * 64 + lane;
    const int r = G >> 3, g = (G & 7) ^ (r & 7);
    bsrc[p] = Bb + (size_t)(n0 + r) * KDIM + g * 8;
  }

  v4f acc[2][8];
  #pragma unroll
  for (int i = 0; i < 2; i++)
    #pragma unroll
    for (int j = 0; j < 8; j++) acc[i][j] = (v4f){0.f, 0.f, 0.f, 0.f};

  const int ma0 = wm + cl, ma1 = wm + 16 + cl;

  #pragma unroll
  for (int k0 = 0; k0 < KDIM; k0 += 64) {
    __syncthreads();
    g2lds16(wsrc0 + k0, Ws + wid * 512);
    g2lds16(wsrc1 + k0, Ws + wid * 512 + 2048);
    #pragma unroll
    for (int p = 0; p < 8; ++p)
      g2lds16(bsrc[p] + k0, Bs + (p * 256 + wid * 64) * 8);
    __syncthreads();
    #pragma unroll
    for (int ks = 0; ks < 2; ++ks) {
      const int gk = ks * 4 + quad;
      v8s fa0 = *(v8s*)&Ws[(ma0 * 8 + (gk ^ (ma0 & 7))) * 8];
      v8s fa1 = *(v8s*)&Ws[(ma1 * 8 + (gk ^ (ma1 & 7))) * 8];
      v8s fb[8];
      #pragma unroll
      for (int j = 0; j < 8; ++j) {
        const int nb = wn + j * 16 + cl;
        fb[j] = *(v8s*)&Bs[(nb * 8 + (gk ^ (nb & 7))) * 8];
      }
      #pragma unroll
      for (int j = 0; j < 8; ++j) {
        acc[0][j] = __builtin_amdgcn_mfma_f32_16x16x32_bf16(fa0, fb[j], acc[0][j], 0, 0, 0);
        acc[1][j] = __builtin_amdgcn_mfma_f32_16x16x32_bf16(fa1, fb[j], acc[1][j], 0, 0, 0);
      }
    }
  }

  float* ft = (float*)S;   // 32 x 260 floats
  #pragma unroll
  for (int h = 0; h < 2; ++h) {
    __syncthreads();
    if ((wid >> 1) == h) {
      #pragma unroll
      for (int mi = 0; mi < 2; mi++)
        #pragma unroll
        for (int j = 0; j < 8; j++) {
          const int col = wn + j * 16 + cl;
          #pragma unroll
          for (int reg = 0; reg < 4; reg++) {
            const int rl = mi * 16 + quad * 4 + reg;
            ft[rl * 260 + col] = acc[mi][j][reg];
          }
        }
    }
    __syncthreads();
    #pragma unroll
    for (int p = 0; p < 8; ++p) {
      const int f4  = p * 256 + tid;
      const int row = f4 >> 6;
      const int c4  = f4 & 63;
      float4 v = *(float4*)&ft[row * 260 + c4 * 4];
      *(float4*)&out[(size_t)(m0 + h * 32 + row) * O_DIM + n0 + c4 * 4] = v;
    }
  }
}

extern "C" void kernel_launch(void* const* d_in, const int* in_sizes, int n_in,
                              void* d_out, int out_size, void* d_ws, size_t ws_size,
                              hipStream_t stream) {
  (void)in_sizes; (void)n_in; (void)out_size; (void)ws_size;
  const float* x       = (const float*)d_in[0];
  const float* P       = (const float*)d_in[1];
  const float* A       = (const float*)d_in[2];
  const float* Bst     = (const float*)d_in[3];
  const float* scaling = (const float*)d_in[4];
  const int*   topk    = (const int*)d_in[5];
  float* out = (float*)d_out;

  char* ws = (char*)d_ws;
  uint16_t* xb     = (uint16_t*)(ws);                 // 33,554,432 B
  uint16_t* Ab     = (uint16_t*)(ws + 33554432);      //  1,048,576 B
  uint16_t* Bb     = (uint16_t*)(ws + 34603008);      //  1,048,576 B
  uint16_t* wbuf   = (uint16_t*)(ws + 35651584);      //  4,194,304 B
  float4*   parts  = (float4*)  (ws + 39845888);      //  4,194,304 B (no alias)

  // grid.x: 0..7 = route chunks (64 tokens/block), 8 = weight prep
  hipLaunchKernelGGL(route_stream, dim3(9, 128), dim3(256), 0, stream,
                     x, P, A, Bst, xb, parts, Ab, Bb);
  hipLaunchKernelGGL(gemm_xa, dim3(512), dim3(256), 0, stream,
                     xb, Ab, parts, scaling, topk, wbuf);
  hipLaunchKernelGGL(gemm_wb, dim3(1024), dim3(256), 0, stream, wbuf, Bb, out);
}